// Round 1
// baseline (242.619 us; speedup 1.0000x reference)
//
#include <hip/hip_runtime.h>

// Problem constants (CausalAttention: B=4, S=2048, D_IN=D_OUT=1024, single head)
#define Bb 4
#define Ss 2048
#define Dd 1024

typedef unsigned short u16;
typedef __bf16 bf16x8 __attribute__((ext_vector_type(8)));
typedef float  f32x4  __attribute__((ext_vector_type(4)));

__device__ inline u16 f2bf(float f) {
  union { float f; unsigned u; } x; x.f = f;
  unsigned u = x.u;
  return (u16)((u + 0x7fffu + ((u >> 16) & 1u)) >> 16);  // RNE
}
__device__ inline float bf2f(u16 h) {
  union { unsigned u; float f; } x; x.u = ((unsigned)h) << 16;
  return x.f;
}

// async global->LDS, 16B per lane. LDS dest is wave-uniform base + lane*16:
// lane order must match LDS contiguity.
__device__ static inline void gl_lds16(const u16* g, u16* l) {
  __builtin_amdgcn_global_load_lds((__attribute__((address_space(1))) const void*)g,
                                   (__attribute__((address_space(3))) void*)l,
                                   16, 0, 0);
}

// raw barrier with compiler memory fences (does NOT drain vmcnt -- that is the
// whole point: counted vmcnt gates keep staging loads in flight across it).
__device__ static inline void qbar() {
  asm volatile("" ::: "memory");
  __builtin_amdgcn_s_barrier();
  asm volatile("" ::: "memory");
}

template <int GATEN>
__device__ __forceinline__ void qk_gate() {
  if constexpr (GATEN == 8) asm volatile("s_waitcnt vmcnt(8)" ::: "memory");
  else if constexpr (GATEN == 4) asm volatile("s_waitcnt vmcnt(4)" ::: "memory");
  else if constexpr (GATEN == 0) asm volatile("s_waitcnt vmcnt(0)" ::: "memory");
}

// ---------------- cast fp32 -> bf16 (x + 3 weights) + lsum zeroing ----------------
__global__ __launch_bounds__(256) void cast_all(const float* __restrict__ x,
                                                const float* __restrict__ wq,
                                                const float* __restrict__ wk,
                                                const float* __restrict__ wv,
                                                u16* __restrict__ xb,
                                                u16* __restrict__ wb,
                                                float* __restrict__ lsum) {
  int id = blockIdx.x;
  if (id < 8) {
    float4 z = {0.f, 0.f, 0.f, 0.f};
    ((float4*)lsum)[id * 256 + threadIdx.x] = z;
  }
  const float* src; u16* dst; int off;
  if (id < 2048) {                      // x: 8M elements
    src = x; dst = xb; off = id * 4096;
  } else {                              // weights: 1M each, 256 blocks per W
    int wi = id - 2048;
    int w = wi >> 8;
    src = (w == 0) ? wq : (w == 1) ? wk : wv;
    dst = wb + (size_t)w * Dd * Dd;
    off = (wi & 255) * 4096;
  }
#pragma unroll
  for (int t = 0; t < 4; t++) {
    int i = off + t * 1024 + threadIdx.x * 4;
    float4 v = *(const float4*)(src + i);
    unsigned p0 = (unsigned)f2bf(v.x) | ((unsigned)f2bf(v.y) << 16);
    unsigned p1 = (unsigned)f2bf(v.z) | ((unsigned)f2bf(v.w) << 16);
    uint2 p; p.x = p0; p.y = p1;
    *(uint2*)(dst + i) = p;
  }
}

// ---------------- shared GEMM core (C = A * B^T), bf16 in, fp32 acc ----------------
// (m97-style 128x128 core -- still used by scores_fused and pv_gemm.)
#define BM 128
#define BN 128

__device__ inline void gemm_tile(const u16* __restrict__ A, int lda,
                                 const u16* __restrict__ Bp, int ldb,
                                 int kBeg, int kEnd,  // multiples of 64
                                 u16* lds, f32x4 acc[4][4]) {
  u16* lA0 = lds;
  u16* lB0 = lds + 4096;
  u16* lA1 = lds + 8192;
  u16* lB1 = lds + 12288;
  const int tid  = threadIdx.x;
  const int lane = tid & 63, wave = tid >> 6;
  const int quad = lane >> 4, r16 = lane & 15;
  const int wm = (wave & 1) * 64, wn = (wave >> 1) * 64;
  const int r0 = tid >> 2, part = tid & 3;  // seg s=q*256+tid -> row=q*64+r0

  for (int k0 = kBeg; k0 < kEnd; k0 += 64) {
    __syncthreads();  // previous halves' ds_reads done before overwrite
#pragma unroll
    for (int q = 0; q < 2; q++) {
      int row = q * 64 + r0;
      int s8 = (q * 256 + tid) * 8;
      const u16* ga = A  + (size_t)row * lda + k0 + part * 8;
      const u16* gb = Bp + (size_t)row * ldb + k0 + part * 8;
      gl_lds16(ga,      lA0 + s8);
      gl_lds16(gb,      lB0 + s8);
      gl_lds16(ga + 32, lA1 + s8);
      gl_lds16(gb + 32, lB1 + s8);
    }
    __syncthreads();
#pragma unroll
    for (int h = 0; h < 2; h++) {
      const u16* la = h ? lA1 : lA0;
      const u16* lb = h ? lB1 : lB0;
      bf16x8 fa[4], fb[4];
#pragma unroll
      for (int t = 0; t < 4; t++)
        fa[t] = *(const bf16x8*)(la + (wm + t * 16 + r16) * 32 + quad * 8);
#pragma unroll
      for (int t = 0; t < 4; t++)
        fb[t] = *(const bf16x8*)(lb + (wn + t * 16 + r16) * 32 + quad * 8);
#pragma unroll
      for (int tm = 0; tm < 4; tm++)
#pragma unroll
        for (int tn = 0; tn < 4; tn++)
          acc[tm][tn] = __builtin_amdgcn_mfma_f32_16x16x32_bf16(fa[tm], fb[tn],
                                                                acc[tm][tn], 0, 0, 0);
    }
  }
}

// ---------------- QKV projection: 256x256 tile, 8-phase counted-vmcnt core -------
// T3+T4+T2+T5 structure (cdna_hip_programming.md S5.5): 512 threads = 8 waves
// (2M x 4N), per-wave 128x64 output, ring of 4 BK=32 LDS buffers (128 KiB).
// Stage tile T+3 while computing tile T (lead ~4 phases >= HBM latency); gate
// with s_waitcnt vmcnt(8) once per K-tile (never 0 in steady state; tail
// drains 8->4->0). Raw s_barrier (no vmcnt drain) -- ledger:
//   prologue stages tiles 0..2 (12 loads), vmcnt(8) => tile0 landed.
//   gate at tile T leaves {A,B}(T+2) + {A,B}(T+3) = 8 outstanding => T+1 landed.
// WAR safe: stage into buf (T-1)&3 issues only after the barrier following the
// MFMA that lgkm-drained that buffer's last ds_reads.
// LDS bank swizzle: 16B-chunk c stored at c ^ ((row>>1)&3), applied on the
// *global source* address (gl_lds dest must stay linear) and on the ds_read
// address (involution; rule 21). Read pattern (16 rows x 4 quads per wave)
// then maps 64 lanes onto 8 disjoint 4-bank groups -> conflict-free.
#define QBK 32

__global__ __launch_bounds__(512, 2) void qkv_gemm256(const u16* __restrict__ xb,
                                                      const u16* __restrict__ wb,
                                                      u16* __restrict__ qkv) {
  __shared__ __align__(16) u16 sh[4 * 16384];  // 4 bufs x (A 8192 + B 8192) u16 = 128 KiB
  u16* const shf = sh;

  const int id  = blockIdx.x;                  // 0..383
  const int swz = (id & 7) * 48 + (id >> 3);   // XCD-contiguous chunks (384%8==0)
  const int zi  = swz >> 7;                    // 0..2 : which weight
  const int rem = swz & 127;
  const int mt  = rem >> 2, nt = rem & 3;      // 32 x 4 tiles
  const int row0 = mt * 256, col0 = nt * 256;
  const u16* A  = xb + (size_t)row0 * Dd;
  const u16* Bp = wb + (size_t)zi * Dd * Dd + (size_t)col0 * Dd;

  const int tid  = threadIdx.x;
  const int lane = tid & 63, wave = tid >> 6;
  const int wr = wave >> 2, wc = wave & 3;     // 2 x 4 wave grid
  const int quad = lane >> 4, r16 = lane & 15;

  // staging: physical 16B slot p (0..1023): row=p>>2, chunk=p&3; source holds
  // logical chunk (p&3) ^ ((row>>1)&3). Two slots/thread: tid, tid+512.
  const int pA0 = tid, pA1 = tid + 512;
  const int r0a = pA0 >> 2, c0a = pA0 & 3;
  const int r1a = pA1 >> 2, c1a = pA1 & 3;
  const u16* aS0 = A  + (size_t)r0a * Dd + (size_t)((c0a ^ ((r0a >> 1) & 3)) * 8);
  const u16* aS1 = A  + (size_t)r1a * Dd + (size_t)((c1a ^ ((r1a >> 1) & 3)) * 8);
  const u16* bS0 = Bp + (size_t)r0a * Dd + (size_t)((c0a ^ ((r0a >> 1) & 3)) * 8);
  const u16* bS1 = Bp + (size_t)r1a * Dd + (size_t)((c1a ^ ((r1a >> 1) & 3)) * 8);

  auto stgA = [&](int S) {
    u16* d = shf + (S & 3) * 16384;
    gl_lds16(aS0 + (size_t)S * QBK, d + pA0 * 8);
    gl_lds16(aS1 + (size_t)S * QBK, d + pA1 * 8);
  };
  auto stgB = [&](int S) {
    u16* d = shf + (S & 3) * 16384 + 8192;
    gl_lds16(bS0 + (size_t)S * QBK, d + pA0 * 8);
    gl_lds16(bS1 + (size_t)S * QBK, d + pA1 * 8);
  };

  // ds_read fragment bases ([256][32] u16 rows; swizzled 16B chunk)
  const int chq  = (quad ^ ((r16 >> 1) & 3)) * 8;
  const int idxA = (wr * 128 + r16) * 32 + chq;  // + m*512
  const int idxB = (wc * 64  + r16) * 32 + chq;  // + n*512

  f32x4 acc[8][4];
#pragma unroll
  for (int m = 0; m < 8; m++)
#pragma unroll
    for (int n = 0; n < 4; n++) acc[m][n] = (f32x4){0.f, 0.f, 0.f, 0.f};
  bf16x8 fb[4];

#define QKV_TILE(U, STG_S, GATEN)                                              \
  {                                                                            \
    const u16* lA = shf + (U) * 16384;                                         \
    const u16* lB = lA + 8192;                                                 \
    bf16x8 fa[4];                                                              \
    _Pragma("unroll") for (int m = 0; m < 4; m++)                              \
        fa[m] = *(const bf16x8*)(lA + idxA + m * 512);                         \
    _Pragma("unroll") for (int n = 0; n < 4; n++)                              \
        fb[n] = *(const bf16x8*)(lB + idxB + n * 512);                         \
    if ((STG_S) >= 0) stgA(STG_S);                                             \
    qbar();                                                                    \
    __builtin_amdgcn_s_setprio(1);                                             \
    _Pragma("unroll") for (int m = 0; m < 4; m++)                              \
      _Pragma("unroll") for (int n = 0; n < 4; n++)                            \
        acc[m][n] = __builtin_amdgcn_mfma_f32_16x16x32_bf16(fa[m], fb[n],      \
                                                            acc[m][n], 0, 0, 0); \
    __builtin_amdgcn_s_setprio(0);                                             \
    qbar();                                                                    \
    _Pragma("unroll") for (int m = 0; m < 4; m++)                              \
        fa[m] = *(const bf16x8*)(lA + idxA + (m + 4) * 512);                   \
    if ((STG_S) >= 0) stgB(STG_S);                                             \
    qk_gate<GATEN>();                                                          \
    qbar();                                                                    \
    __builtin_amdgcn_s_setprio(1);                                             \
    _Pragma("unroll") for (int m = 0; m < 4; m++)                              \
      _Pragma("unroll") for (int n = 0; n < 4; n++)                            \
        acc[m + 4][n] = __builtin_amdgcn_mfma_f32_16x16x32_bf16(fa[m], fb[n],  \
                                                                acc[m + 4][n], 0, 0, 0); \
    __builtin_amdgcn_s_setprio(0);                                             \
    qbar();                                                                    \
  }

  // prologue: stage tiles 0..2, land tile 0 (leave 8 = tiles 1,2 in flight)
  stgA(0); stgB(0); stgA(1); stgB(1); stgA(2); stgB(2);
  asm volatile("s_waitcnt vmcnt(8)" ::: "memory");
  qbar();

#pragma unroll 1
  for (int T = 0; T < 28; T++) QKV_TILE(T & 3, T + 3, 8);
  QKV_TILE(0, 31, 8);   // T=28
  QKV_TILE(1, -1, 4);   // T=29
  QKV_TILE(2, -1, 0);   // T=30
  QKV_TILE(3, -1, -1);  // T=31
#undef QKV_TILE

  u16* out = qkv + (size_t)zi * ((size_t)Bb * Ss * Dd);
#pragma unroll
  for (int m = 0; m < 8; m++) {
    int rr = row0 + wr * 128 + m * 16 + quad * 4;
#pragma unroll
    for (int n = 0; n < 4; n++) {
      int cc = col0 + wc * 64 + n * 16 + r16;
#pragma unroll
      for (int r = 0; r < 4; r++)
        out[(size_t)(rr + r) * Dd + cc] = f2bf(acc[m][n][r]);
    }
  }
}

// ---------------- fused scores + rowsum + V-transpose ----------------
// Blocks [0,544): lower-tri score tiles -> sc = exp(QK^T/32) (diag masked),
//   per-row partial sums atomically added into lsum (bf16-rounded p summed so
//   numerator/denominator rounding match).
// Blocks [544,1024): V transpose, grid-stride over 2048 64x64 tiles.
__global__ __launch_bounds__(256) void scores_fused(const u16* __restrict__ qb,
                                                    const u16* __restrict__ kb,
                                                    const u16* __restrict__ vb,
                                                    u16* __restrict__ sc,
                                                    u16* __restrict__ vt,
                                                    float* __restrict__ lsum) {
  __shared__ __align__(16) u16 shmem[16384];
  const int id = blockIdx.x;
  const int tid = threadIdx.x;

  if (id >= 544) {  // ---- transpose role ----
    const int bid = id - 544;            // 0..479
    u16 (*t)[72] = (u16(*)[72])shmem;    // 64x72 u16 = 9216 <= 16384
    for (int u = bid; u < 2048; u += 480) {
      const int b = u >> 9, rem = u & 511;
      const int e0 = (rem >> 5) * 64, s0 = (rem & 31) * 64;
      const u16* src = vb + (size_t)b * Ss * Dd;
      u16* dst = vt + (size_t)b * Dd * Ss;
      if (u != bid) __syncthreads();
#pragma unroll
      for (int gg = tid; gg < 512; gg += 256) {
        int row = gg >> 3, prt = gg & 7;
        uint4 v = *(const uint4*)(src + (size_t)(s0 + row) * Dd + e0 + prt * 8);
        const u16* pv = (const u16*)&v;
#pragma unroll
        for (int jj = 0; jj < 8; jj++) t[prt * 8 + jj][row] = pv[jj];
      }
      __syncthreads();
#pragma unroll
      for (int gg = tid; gg < 512; gg += 256) {
        int ee = gg >> 3, prt = gg & 7;
        uint4 v = *(const uint4*)(&t[ee][prt * 8]);
        *(uint4*)(dst + (size_t)(e0 + ee) * Ss + s0 + prt * 8) = v;
      }
    }
    return;
  }

  // ---- scores role ----
  // XCD swizzle: 17 consecutive tri-ids per XCD per batch (136 = 8*17).
  const int xcd = id & 7, j = id >> 3;   // j 0..67
  const int b = j / 17, tloc = j - b * 17;
  const int t = xcd * 17 + tloc;         // 0..135 lower-tri index
  int it = (int)((sqrtf(8.f * (float)t + 1.f) - 1.f) * 0.5f);
  while ((it + 1) * (it + 2) / 2 <= t) it++;
  while (it * (it + 1) / 2 > t) it--;
  const int jt = t - it * (it + 1) / 2;

  const u16* A  = qb + (size_t)b * Ss * Dd + (size_t)it * BM * Dd;
  const u16* Bp = kb + (size_t)b * Ss * Dd + (size_t)jt * BN * Dd;
  f32x4 acc[4][4];
  const f32x4 zero = {0.f, 0.f, 0.f, 0.f};
#pragma unroll
  for (int tm = 0; tm < 4; tm++)
#pragma unroll
    for (int tn = 0; tn < 4; tn++) acc[tm][tn] = zero;

  gemm_tile(A, Dd, Bp, Dd, 0, Dd, shmem, acc);

  // Unnormalized exp (|s/32| << 88 so fp32 exp safe without max-subtraction).
  u16* out = sc + (size_t)b * Ss * Ss;
  float* lr = lsum + (size_t)b * Ss;
  const int lane = tid & 63, wave = tid >> 6;
  const int quad = lane >> 4, r16 = lane & 15;
  const int wm = (wave & 1) * 64, wn = (wave >> 1) * 64;
#pragma unroll
  for (int tm = 0; tm < 4; tm++) {
    float psum[4] = {0.f, 0.f, 0.f, 0.f};  // per r, summed over tn
#pragma unroll
    for (int tn = 0; tn < 4; tn++) {
      int rr = it * BM + wm + tm * 16 + quad * 4;
      int cc = jt * BN + wn + tn * 16 + r16;
#pragma unroll
      for (int r = 0; r < 4; r++) {
        float p = 0.f;
        u16 h = 0;
        if (cc <= rr + r) {
          h = f2bf(__expf(acc[tm][tn][r] * 0.03125f));
          p = bf2f(h);  // sum the bf16-rounded value (matches stored numerator)
        }
        out[(size_t)(rr + r) * Ss + cc] = h;
        psum[r] += p;
      }
    }
#pragma unroll
    for (int r = 0; r < 4; r++) {
      float s = psum[r];
      s += __shfl_xor(s, 1);
      s += __shfl_xor(s, 2);
      s += __shfl_xor(s, 4);
      s += __shfl_xor(s, 8);
      if (r16 == 0) {
        int row = it * BM + wm + tm * 16 + quad * 4 + r;
        atomicAdd(&lr[row], s);
      }
    }
  }
}

// ---------------- PV: O[q,e] = (1/l[q]) * sum_k sc[q,k] Vt[e,k] ----------------
// XCD-grouped schedule: xcd=idx&7, slot=idx>>3; qp=slot>>3 (0..7), col=slot&7.
// b=qp&3, it=(qp>>2)?15-xcd:xcd. The 8 col-tiles of one (b,it) are consecutive
// slots on ONE XCD -> sc A-panel fetched ~once from HBM (not 8x) and vt[b]
// reused in that XCD's L2. Each XCD gets its {xcd, 15-xcd} -> uniform 17
// tile-K per XCD regardless of block->CU pairing granularity.
__global__ __launch_bounds__(256) void pv_gemm(const u16* __restrict__ sc,
                                               const u16* __restrict__ vt,
                                               const float* __restrict__ lsum,
                                               float* __restrict__ out) {
  __shared__ __align__(16) u16 shmem[16384];
  const int idx = blockIdx.x;            // 0..511
  const int xcd = idx & 7, slot = idx >> 3;
  const int qp = slot >> 3, col = slot & 7;
  const int b = qp & 3;
  const int it = (qp >> 2) ? (15 - xcd) : xcd;
  const int row0 = it * BM;
  const int col0 = col * BN;             // N = 1024
  const u16* A  = sc + (size_t)b * Ss * Ss + (size_t)row0 * Ss;
  const u16* Bp = vt + (size_t)b * Dd * Ss + (size_t)col0 * Ss;
  f32x4 acc[4][4];
  const f32x4 zero = {0.f, 0.f, 0.f, 0.f};
#pragma unroll
  for (int tm = 0; tm < 4; tm++)
#pragma unroll
    for (int tn = 0; tn < 4; tn++) acc[tm][tn] = zero;

  // causal: P[q,k]==0 for k > q (incl. zero-filled diag tile), K-loop clipped
  gemm_tile(A, Ss, Bp, Ss, 0, row0 + BM, shmem, acc);

  float* o = out + (size_t)b * Ss * Dd;
  const float* lr = lsum + (size_t)b * Ss;
  const int lane = threadIdx.x & 63, wave = threadIdx.x >> 6;
  const int quad = lane >> 4, r16 = lane & 15;
  const int wm = (wave & 1) * 64, wn = (wave >> 1) * 64;
#pragma unroll
  for (int tm = 0; tm < 4; tm++) {
    int rbase = row0 + wm + tm * 16 + quad * 4;
    float s0 = 1.f / lr[rbase], s1 = 1.f / lr[rbase + 1];
    float s2 = 1.f / lr[rbase + 2], s3 = 1.f / lr[rbase + 3];
#pragma unroll
    for (int tn = 0; tn < 4; tn++) {
      int cc = col0 + wn + tn * 16 + r16;
      o[(size_t)(rbase + 0) * Dd + cc] = acc[tm][tn][0] * s0;
      o[(size_t)(rbase + 1) * Dd + cc] = acc[tm][tn][1] * s1;
      o[(size_t)(rbase + 2) * Dd + cc] = acc[tm][tn][2] * s2;
      o[(size_t)(rbase + 3) * Dd + cc] = acc[tm][tn][3] * s3;
    }
  }
}

// ---------------- launch ----------------
// Workspace layout (bytes), total 106,987,520 (~102 MB):
//   qkv : [0, 50331648)           q,k,v bf16, each 16 MB
//   sc  : [50331648, 83886080)    exp-scores bf16, 32 MB
//   xb  : [83886080, 100663296)   x bf16 16 MB; REUSED as vt after qkv_gemm256
//   wb  : [100663296, 106954752)  wq|wk|wv bf16, 6 MB
//   lsum: [106954752, 106987520)  per-row sum fp32, 32 KB (zeroed by cast_all)
extern "C" void kernel_launch(void* const* d_in, const int* in_sizes, int n_in,
                              void* d_out, int out_size, void* d_ws, size_t ws_size,
                              hipStream_t stream) {
  const float* x  = (const float*)d_in[0];
  const float* wq = (const float*)d_in[1];
  const float* wk = (const float*)d_in[2];
  const float* wv = (const float*)d_in[3];
  float* out = (float*)d_out;
  char* ws = (char*)d_ws;
  if (ws_size < 106987520u) return;  // clean fail rather than OOB corruption

  u16* qkv  = (u16*)(ws);
  u16* sc   = (u16*)(ws + 50331648u);
  u16* xb   = (u16*)(ws + 83886080u);
  u16* vt   = xb;  // alias: x dead after qkv_gemm256
  u16* wb   = (u16*)(ws + 100663296u);
  float* lsum = (float*)(ws + 106954752u);

  const size_t nQ = (size_t)Bb * Ss * Dd;  // 8388608

  cast_all<<<2816, 256, 0, stream>>>(x, wq, wk, wv, xb, wb, lsum);
  qkv_gemm256<<<384, 512, 0, stream>>>(xb, wb, qkv);
  scores_fused<<<1024, 256, 0, stream>>>(qkv, qkv + nQ, qkv + 2 * nQ, sc, vt, lsum);
  pv_gemm<<<512, 256, 0, stream>>>(sc, vt, lsum, out);
}

// Round 2
// 238.723 us; speedup vs baseline: 1.0163x; 1.0163x over previous
//
#include <hip/hip_runtime.h>

// Problem constants (CausalAttention: B=4, S=2048, D_IN=D_OUT=1024, single head)
#define Bb 4
#define Ss 2048
#define Dd 1024

typedef unsigned short u16;
typedef __bf16 bf16x8 __attribute__((ext_vector_type(8)));
typedef float  f32x4  __attribute__((ext_vector_type(4)));

__device__ inline u16 f2bf(float f) {
  union { float f; unsigned u; } x; x.f = f;
  unsigned u = x.u;
  return (u16)((u + 0x7fffu + ((u >> 16) & 1u)) >> 16);  // RNE
}
__device__ inline float bf2f(u16 h) {
  union { unsigned u; float f; } x; x.u = ((unsigned)h) << 16;
  return x.f;
}

// async global->LDS, 16B per lane. LDS dest is wave-uniform base + lane*16:
// lane order must match LDS contiguity.
__device__ static inline void gl_lds16(const u16* g, u16* l) {
  __builtin_amdgcn_global_load_lds((__attribute__((address_space(1))) const void*)g,
                                   (__attribute__((address_space(3))) void*)l,
                                   16, 0, 0);
}

// raw barrier with compiler memory fences (does NOT drain vmcnt -- counted
// vmcnt gates keep staging loads in flight across it).
__device__ static inline void qbar() {
  asm volatile("" ::: "memory");
  __builtin_amdgcn_s_barrier();
  asm volatile("" ::: "memory");
}

template <int GATEN>
__device__ __forceinline__ void qk_gate() {
  if constexpr (GATEN == 6) asm volatile("s_waitcnt vmcnt(6)" ::: "memory");
  else if constexpr (GATEN == 3) asm volatile("s_waitcnt vmcnt(3)" ::: "memory");
  else if constexpr (GATEN == 0) asm volatile("s_waitcnt vmcnt(0)" ::: "memory");
}

// ---------------- cast fp32 -> bf16 (x + 3 weights) + lsum zeroing ----------------
__global__ __launch_bounds__(256) void cast_all(const float* __restrict__ x,
                                                const float* __restrict__ wq,
                                                const float* __restrict__ wk,
                                                const float* __restrict__ wv,
                                                u16* __restrict__ xb,
                                                u16* __restrict__ wb,
                                                float* __restrict__ lsum) {
  int id = blockIdx.x;
  if (id < 8) {
    float4 z = {0.f, 0.f, 0.f, 0.f};
    ((float4*)lsum)[id * 256 + threadIdx.x] = z;
  }
  const float* src; u16* dst; int off;
  if (id < 2048) {                      // x: 8M elements
    src = x; dst = xb; off = id * 4096;
  } else {                              // weights: 1M each, 256 blocks per W
    int wi = id - 2048;
    int w = wi >> 8;
    src = (w == 0) ? wq : (w == 1) ? wk : wv;
    dst = wb + (size_t)w * Dd * Dd;
    off = (wi & 255) * 4096;
  }
#pragma unroll
  for (int t = 0; t < 4; t++) {
    int i = off + t * 1024 + threadIdx.x * 4;
    float4 v = *(const float4*)(src + i);
    unsigned p0 = (unsigned)f2bf(v.x) | ((unsigned)f2bf(v.y) << 16);
    unsigned p1 = (unsigned)f2bf(v.z) | ((unsigned)f2bf(v.w) << 16);
    uint2 p; p.x = p0; p.y = p1;
    *(uint2*)(dst + i) = p;
  }
}

// ---------------- shared GEMM core (C = A * B^T), bf16 in, fp32 acc ----------------
// (m97-style 128x128 core -- used by scores_fused and pv_gemm.)
#define BM 128
#define BN 128

__device__ inline void gemm_tile(const u16* __restrict__ A, int lda,
                                 const u16* __restrict__ Bp, int ldb,
                                 int kBeg, int kEnd,  // multiples of 64
                                 u16* lds, f32x4 acc[4][4]) {
  u16* lA0 = lds;
  u16* lB0 = lds + 4096;
  u16* lA1 = lds + 8192;
  u16* lB1 = lds + 12288;
  const int tid  = threadIdx.x;
  const int lane = tid & 63, wave = tid >> 6;
  const int quad = lane >> 4, r16 = lane & 15;
  const int wm = (wave & 1) * 64, wn = (wave >> 1) * 64;
  const int r0 = tid >> 2, part = tid & 3;  // seg s=q*256+tid -> row=q*64+r0

  for (int k0 = kBeg; k0 < kEnd; k0 += 64) {
    __syncthreads();  // previous halves' ds_reads done before overwrite
#pragma unroll
    for (int q = 0; q < 2; q++) {
      int row = q * 64 + r0;
      int s8 = (q * 256 + tid) * 8;
      const u16* ga = A  + (size_t)row * lda + k0 + part * 8;
      const u16* gb = Bp + (size_t)row * ldb + k0 + part * 8;
      gl_lds16(ga,      lA0 + s8);
      gl_lds16(gb,      lB0 + s8);
      gl_lds16(ga + 32, lA1 + s8);
      gl_lds16(gb + 32, lB1 + s8);
    }
    __syncthreads();
#pragma unroll
    for (int h = 0; h < 2; h++) {
      const u16* la = h ? lA1 : lA0;
      const u16* lb = h ? lB1 : lB0;
      bf16x8 fa[4], fb[4];
#pragma unroll
      for (int t = 0; t < 4; t++)
        fa[t] = *(const bf16x8*)(la + (wm + t * 16 + r16) * 32 + quad * 8);
#pragma unroll
      for (int t = 0; t < 4; t++)
        fb[t] = *(const bf16x8*)(lb + (wn + t * 16 + r16) * 32 + quad * 8);
#pragma unroll
      for (int tm = 0; tm < 4; tm++)
#pragma unroll
        for (int tn = 0; tn < 4; tn++)
          acc[tm][tn] = __builtin_amdgcn_mfma_f32_16x16x32_bf16(fa[tm], fb[tn],
                                                                acc[tm][tn], 0, 0, 0);
    }
  }
}

// ---------------- QKV projection: 256x128 tile, counted-vmcnt phase core --------
// Grid 768 = (8192/256)x(1024/128)x3 = EXACTLY 3 full rounds at 1 block/CU
// (round-1 post-mortem: 384 blocks -> half-empty 2nd round = 25% idle).
// 512 threads = 8 waves (4M x 2N), per-wave 64x64 output (acc[4][4]).
// Ring of 4 BK=32 buffers (A 16KB + B 8KB = 24KB each, 96 KiB total).
// Per phase (one K-tile): {8x ds_read_b128; stage tile T+3 (3x gl_lds);
// gate vmcnt(6); barrier; setprio(1); 16 MFMA; setprio(0); barrier}.
// Ledger (3 loads/phase): prologue stages 0..2 (9), vmcnt(6) => tile0 landed.
// Gate at T leaves {T+2,T+3}=6 outstanding => T+1 landed. Tail 6->3->0.
// WAR: stage(T+3) hits buf (T-1)&3, whose reads were lgkm-drained before
// phase T-1's MFMA; phase T-1's closing barrier orders all waves before it.
// LDS bank swizzle (measured 0 conflicts in r1): 16B-chunk c stored at
// c ^ ((row>>1)&3), applied on the *global source* address (gl_lds dest must
// stay linear) and on the ds_read address (involution, rule 21).
#define QBK 32

__global__ __launch_bounds__(512, 1) void qkv_gemm3(const u16* __restrict__ xb,
                                                    const u16* __restrict__ wb,
                                                    u16* __restrict__ qkv) {
  __shared__ __align__(16) u16 sh[4 * 12288];  // 4 bufs x 24 KB = 96 KiB

  const int id  = blockIdx.x;                  // 0..767
  const int swz = (id & 7) * 96 + (id >> 3);   // XCD-contiguous (768%8==0)
  const int zi  = swz >> 8;                    // 0..2 : which weight
  const int rem = swz & 255;
  const int mt  = rem >> 3, nt = rem & 7;      // 32 x 8 tiles
  const int row0 = mt * 256, col0 = nt * 128;
  const u16* A  = xb + (size_t)row0 * Dd;
  const u16* Bp = wb + (size_t)zi * Dd * Dd + (size_t)col0 * Dd;

  const int tid  = threadIdx.x;
  const int lane = tid & 63, wave = tid >> 6;
  const int wr = wave >> 1, wc = wave & 1;     // 4M x 2N wave grid
  const int quad = lane >> 4, r16 = lane & 15;

  // staging: A = 1024 16B-slots (2/thread: tid, tid+512), B = 512 (1/thread).
  // physical slot p: row = p>>2, phys chunk = p&3; source holds logical chunk
  // (p&3) ^ ((row>>1)&3).
  const int pA0 = tid, pA1 = tid + 512;
  const int r0a = pA0 >> 2, c0a = pA0 & 3;
  const int r1a = pA1 >> 2, c1a = pA1 & 3;
  const u16* aS0 = A  + (size_t)r0a * Dd + (size_t)((c0a ^ ((r0a >> 1) & 3)) * 8);
  const u16* aS1 = A  + (size_t)r1a * Dd + (size_t)((c1a ^ ((r1a >> 1) & 3)) * 8);
  const u16* bS0 = Bp + (size_t)r0a * Dd + (size_t)((c0a ^ ((r0a >> 1) & 3)) * 8);

  auto stg = [&](int S) {
    u16* d = sh + (S & 3) * 12288;             // A at d, B at d+8192 (u16 units)
    gl_lds16(aS0 + (size_t)S * QBK, d + pA0 * 8);
    gl_lds16(aS1 + (size_t)S * QBK, d + pA1 * 8);
    gl_lds16(bS0 + (size_t)S * QBK, d + 8192 + pA0 * 8);
  };

  // ds_read fragment bases (rows of 32 u16 = 64 B; swizzled 16B chunk).
  // row = base16 + r16 with base16 multiple of 16 -> (row>>1)&3 == (r16>>1)&3.
  const int chq  = (quad ^ ((r16 >> 1) & 3)) * 8;
  const int idxA = (wr * 64 + r16) * 32 + chq;  // + m*512
  const int idxB = (wc * 64 + r16) * 32 + chq;  // + n*512

  f32x4 acc[4][4];
#pragma unroll
  for (int m = 0; m < 4; m++)
#pragma unroll
    for (int n = 0; n < 4; n++) acc[m][n] = (f32x4){0.f, 0.f, 0.f, 0.f};

#define QTILE(U, STG_S, GATEN)                                                 \
  {                                                                            \
    const u16* lA = sh + (U) * 12288;                                          \
    const u16* lB = lA + 8192;                                                 \
    bf16x8 fa[4], fb[4];                                                       \
    _Pragma("unroll") for (int m = 0; m < 4; m++)                              \
        fa[m] = *(const bf16x8*)(lA + idxA + m * 512);                         \
    _Pragma("unroll") for (int n = 0; n < 4; n++)                              \
        fb[n] = *(const bf16x8*)(lB + idxB + n * 512);                         \
    if ((STG_S) >= 0) stg(STG_S);                                              \
    qk_gate<GATEN>();                                                          \
    qbar();                                                                    \
    __builtin_amdgcn_s_setprio(1);                                             \
    _Pragma("unroll") for (int m = 0; m < 4; m++)                              \
      _Pragma("unroll") for (int n = 0; n < 4; n++)                            \
        acc[m][n] = __builtin_amdgcn_mfma_f32_16x16x32_bf16(fa[m], fb[n],      \
                                                            acc[m][n], 0, 0, 0); \
    __builtin_amdgcn_s_setprio(0);                                             \
    qbar();                                                                    \
  }

  // prologue: stage tiles 0..2 (9 loads), land tile 0 (leave 6 in flight)
  stg(0); stg(1); stg(2);
  asm volatile("s_waitcnt vmcnt(6)" ::: "memory");
  qbar();

#pragma unroll 1
  for (int T = 0; T < 29; T++) QTILE(T & 3, T + 3, 6);
  QTILE(1, -1, 3);   // T=29: outstanding {30:3, 31:3} -> gate 3 => 30 landed
  QTILE(2, -1, 0);   // T=30: gate 0 => 31 landed
  QTILE(3, -1, -1);  // T=31
#undef QTILE

  u16* out = qkv + (size_t)zi * ((size_t)Bb * Ss * Dd);
#pragma unroll
  for (int m = 0; m < 4; m++) {
    int rr = row0 + wr * 64 + m * 16 + quad * 4;
#pragma unroll
    for (int n = 0; n < 4; n++) {
      int cc = col0 + wc * 64 + n * 16 + r16;
#pragma unroll
      for (int r = 0; r < 4; r++)
        out[(size_t)(rr + r) * Dd + cc] = f2bf(acc[m][n][r]);
    }
  }
}

// ---------------- fused scores + rowsum + V-transpose ----------------
// Blocks [0,544): lower-tri score tiles -> sc = exp(QK^T/32) (diag masked),
//   per-row partial sums atomically added into lsum (bf16-rounded p summed so
//   numerator/denominator rounding match).
// Blocks [544,1024): V transpose, grid-stride over 2048 64x64 tiles.
__global__ __launch_bounds__(256) void scores_fused(const u16* __restrict__ qb,
                                                    const u16* __restrict__ kb,
                                                    const u16* __restrict__ vb,
                                                    u16* __restrict__ sc,
                                                    u16* __restrict__ vt,
                                                    float* __restrict__ lsum) {
  __shared__ __align__(16) u16 shmem[16384];
  const int id = blockIdx.x;
  const int tid = threadIdx.x;

  if (id >= 544) {  // ---- transpose role ----
    const int bid = id - 544;            // 0..479
    u16 (*t)[72] = (u16(*)[72])shmem;    // 64x72 u16 = 9216 <= 16384
    for (int u = bid; u < 2048; u += 480) {
      const int b = u >> 9, rem = u & 511;
      const int e0 = (rem >> 5) * 64, s0 = (rem & 31) * 64;
      const u16* src = vb + (size_t)b * Ss * Dd;
      u16* dst = vt + (size_t)b * Dd * Ss;
      if (u != bid) __syncthreads();
#pragma unroll
      for (int gg = tid; gg < 512; gg += 256) {
        int row = gg >> 3, prt = gg & 7;
        uint4 v = *(const uint4*)(src + (size_t)(s0 + row) * Dd + e0 + prt * 8);
        const u16* pv = (const u16*)&v;
#pragma unroll
        for (int jj = 0; jj < 8; jj++) t[prt * 8 + jj][row] = pv[jj];
      }
      __syncthreads();
#pragma unroll
      for (int gg = tid; gg < 512; gg += 256) {
        int ee = gg >> 3, prt = gg & 7;
        uint4 v = *(const uint4*)(&t[ee][prt * 8]);
        *(uint4*)(dst + (size_t)(e0 + ee) * Ss + s0 + prt * 8) = v;
      }
    }
    return;
  }

  // ---- scores role ----
  // XCD swizzle: 17 consecutive tri-ids per XCD per batch (136 = 8*17).
  const int xcd = id & 7, j = id >> 3;   // j 0..67
  const int b = j / 17, tloc = j - b * 17;
  const int t = xcd * 17 + tloc;         // 0..135 lower-tri index
  int it = (int)((sqrtf(8.f * (float)t + 1.f) - 1.f) * 0.5f);
  while ((it + 1) * (it + 2) / 2 <= t) it++;
  while (it * (it + 1) / 2 > t) it--;
  const int jt = t - it * (it + 1) / 2;

  const u16* A  = qb + (size_t)b * Ss * Dd + (size_t)it * BM * Dd;
  const u16* Bp = kb + (size_t)b * Ss * Dd + (size_t)jt * BN * Dd;
  f32x4 acc[4][4];
  const f32x4 zero = {0.f, 0.f, 0.f, 0.f};
#pragma unroll
  for (int tm = 0; tm < 4; tm++)
#pragma unroll
    for (int tn = 0; tn < 4; tn++) acc[tm][tn] = zero;

  gemm_tile(A, Dd, Bp, Dd, 0, Dd, shmem, acc);

  // Unnormalized exp (|s/32| << 88 so fp32 exp safe without max-subtraction).
  u16* out = sc + (size_t)b * Ss * Ss;
  float* lr = lsum + (size_t)b * Ss;
  const int lane = tid & 63, wave = tid >> 6;
  const int quad = lane >> 4, r16 = lane & 15;
  const int wm = (wave & 1) * 64, wn = (wave >> 1) * 64;
#pragma unroll
  for (int tm = 0; tm < 4; tm++) {
    float psum[4] = {0.f, 0.f, 0.f, 0.f};  // per r, summed over tn
#pragma unroll
    for (int tn = 0; tn < 4; tn++) {
      int rr = it * BM + wm + tm * 16 + quad * 4;
      int cc = jt * BN + wn + tn * 16 + r16;
#pragma unroll
      for (int r = 0; r < 4; r++) {
        float p = 0.f;
        u16 h = 0;
        if (cc <= rr + r) {
          h = f2bf(__expf(acc[tm][tn][r] * 0.03125f));
          p = bf2f(h);  // sum the bf16-rounded value (matches stored numerator)
        }
        out[(size_t)(rr + r) * Ss + cc] = h;
        psum[r] += p;
      }
    }
#pragma unroll
    for (int r = 0; r < 4; r++) {
      float s = psum[r];
      s += __shfl_xor(s, 1);
      s += __shfl_xor(s, 2);
      s += __shfl_xor(s, 4);
      s += __shfl_xor(s, 8);
      if (r16 == 0) {
        int row = it * BM + wm + tm * 16 + quad * 4 + r;
        atomicAdd(&lr[row], s);
      }
    }
  }
}

// ---------------- PV: O[q,e] = (1/l[q]) * sum_k sc[q,k] Vt[e,k] ----------------
// XCD-grouped schedule: xcd=idx&7, slot=idx>>3; qp=slot>>3 (0..7), col=slot&7.
// b=qp&3, it=(qp>>2)?15-xcd:xcd. The 8 col-tiles of one (b,it) are consecutive
// slots on ONE XCD -> sc A-panel fetched ~once from HBM (not 8x) and vt[b]
// reused in that XCD's L2. Each XCD gets its {xcd, 15-xcd} -> uniform 17
// tile-K per XCD regardless of block->CU pairing granularity.
__global__ __launch_bounds__(256) void pv_gemm(const u16* __restrict__ sc,
                                               const u16* __restrict__ vt,
                                               const float* __restrict__ lsum,
                                               float* __restrict__ out) {
  __shared__ __align__(16) u16 shmem[16384];
  const int idx = blockIdx.x;            // 0..511
  const int xcd = idx & 7, slot = idx >> 3;
  const int qp = slot >> 3, col = slot & 7;
  const int b = qp & 3;
  const int it = (qp >> 2) ? (15 - xcd) : xcd;
  const int row0 = it * BM;
  const int col0 = col * BN;             // N = 1024
  const u16* A  = sc + (size_t)b * Ss * Ss + (size_t)row0 * Ss;
  const u16* Bp = vt + (size_t)b * Dd * Ss + (size_t)col0 * Ss;
  f32x4 acc[4][4];
  const f32x4 zero = {0.f, 0.f, 0.f, 0.f};
#pragma unroll
  for (int tm = 0; tm < 4; tm++)
#pragma unroll
    for (int tn = 0; tn < 4; tn++) acc[tm][tn] = zero;

  // causal: P[q,k]==0 for k > q (incl. zero-filled diag tile), K-loop clipped
  gemm_tile(A, Ss, Bp, Ss, 0, row0 + BM, shmem, acc);

  float* o = out + (size_t)b * Ss * Dd;
  const float* lr = lsum + (size_t)b * Ss;
  const int lane = threadIdx.x & 63, wave = threadIdx.x >> 6;
  const int quad = lane >> 4, r16 = lane & 15;
  const int wm = (wave & 1) * 64, wn = (wave >> 1) * 64;
#pragma unroll
  for (int tm = 0; tm < 4; tm++) {
    int rbase = row0 + wm + tm * 16 + quad * 4;
    float s0 = 1.f / lr[rbase], s1 = 1.f / lr[rbase + 1];
    float s2 = 1.f / lr[rbase + 2], s3 = 1.f / lr[rbase + 3];
#pragma unroll
    for (int tn = 0; tn < 4; tn++) {
      int cc = col0 + wn + tn * 16 + r16;
      o[(size_t)(rbase + 0) * Dd + cc] = acc[tm][tn][0] * s0;
      o[(size_t)(rbase + 1) * Dd + cc] = acc[tm][tn][1] * s1;
      o[(size_t)(rbase + 2) * Dd + cc] = acc[tm][tn][2] * s2;
      o[(size_t)(rbase + 3) * Dd + cc] = acc[tm][tn][3] * s3;
    }
  }
}

// ---------------- launch ----------------
// Workspace layout (bytes), total 106,987,520 (~102 MB):
//   qkv : [0, 50331648)           q,k,v bf16, each 16 MB
//   sc  : [50331648, 83886080)    exp-scores bf16, 32 MB
//   xb  : [83886080, 100663296)   x bf16 16 MB; REUSED as vt after qkv_gemm3
//   wb  : [100663296, 106954752)  wq|wk|wv bf16, 6 MB
//   lsum: [106954752, 106987520)  per-row sum fp32, 32 KB (zeroed by cast_all)
extern "C" void kernel_launch(void* const* d_in, const int* in_sizes, int n_in,
                              void* d_out, int out_size, void* d_ws, size_t ws_size,
                              hipStream_t stream) {
  const float* x  = (const float*)d_in[0];
  const float* wq = (const float*)d_in[1];
  const float* wk = (const float*)d_in[2];
  const float* wv = (const float*)d_in[3];
  float* out = (float*)d_out;
  char* ws = (char*)d_ws;
  if (ws_size < 106987520u) return;  // clean fail rather than OOB corruption

  u16* qkv  = (u16*)(ws);
  u16* sc   = (u16*)(ws + 50331648u);
  u16* xb   = (u16*)(ws + 83886080u);
  u16* vt   = xb;  // alias: x dead after qkv_gemm3
  u16* wb   = (u16*)(ws + 100663296u);
  float* lsum = (float*)(ws + 106954752u);

  const size_t nQ = (size_t)Bb * Ss * Dd;  // 8388608

  cast_all<<<2816, 256, 0, stream>>>(x, wq, wk, wv, xb, wb, lsum);
  qkv_gemm3<<<768, 512, 0, stream>>>(xb, wb, qkv);
  scores_fused<<<1024, 256, 0, stream>>>(qkv, qkv + nQ, qkv + 2 * nQ, sc, vt, lsum);
  pv_gemm<<<512, 256, 0, stream>>>(sc, vt, lsum, out);
}